// Round 1
// baseline (152.741 us; speedup 1.0000x reference)
//
#include <hip/hip_runtime.h>
#include <math.h>

// Match x86 reference LAPACK (no FMA contraction anywhere in the emulation).
#pragma clang fp contract(off)

#define NIT 35      // provable: prob=min(...,0.99)<=0.99 => k<=35.49 => reason<=35 => no update past it=34
#define BB  32
#define NPTS 32768

// ---------------- LAPACK helpers (fp32, faithful) ----------------

__device__ __forceinline__ float slapy2f(float x, float y){
  float xa = fabsf(x), ya = fabsf(y);
  float w = fmaxf(xa, ya), z = fminf(xa, ya);
  if (z == 0.0f) return w;
  float q = z / w;
  return w * sqrtf(1.0f + q*q);
}

// LAPACK >= 3.10 slartg (modern OpenBLAS as shipped with numpy/scipy).
// (Pre-3.10 fallback, if needed next round: c may be negative when |f|<=|g|.)
__device__ __forceinline__ void slartgf(float f, float g, float* cs, float* sn, float* r){
  if (g == 0.0f){ *cs = 1.0f; *sn = 0.0f; *r = f; return; }
  if (f == 0.0f){ *cs = 0.0f; *sn = copysignf(1.0f, g); *r = fabsf(g); return; }
  float f1 = fabsf(f);
  float d  = sqrtf(f*f + g*g);
  *cs = f1 / d;
  *r  = copysignf(d, f);
  *sn = g / (*r);
}

__device__ void slaev2f(float a, float b, float c,
                        float* rt1, float* rt2, float* cs1, float* sn1){
  float sm  = a + c;
  float df  = a - c;
  float adf = fabsf(df);
  float tb  = b + b;
  float ab  = fabsf(tb);
  float acmx, acmn;
  if (fabsf(a) > fabsf(c)){ acmx = a; acmn = c; } else { acmx = c; acmn = a; }
  float rt;
  if (adf > ab){ float q = ab/adf; rt = adf*sqrtf(1.0f + q*q); }
  else if (adf < ab){ float q = adf/ab; rt = ab*sqrtf(1.0f + q*q); }
  else rt = ab*sqrtf(2.0f);
  int sgn1;
  if (sm < 0.0f){
    *rt1 = 0.5f*(sm - rt); sgn1 = -1;
    *rt2 = (acmx / *rt1)*acmn - (b / *rt1)*b;
  } else if (sm > 0.0f){
    *rt1 = 0.5f*(sm + rt); sgn1 = 1;
    *rt2 = (acmx / *rt1)*acmn - (b / *rt1)*b;
  } else {
    *rt1 = 0.5f*rt; *rt2 = -0.5f*rt; sgn1 = 1;
  }
  float cs; int sgn2;
  if (df >= 0.0f){ cs = df + rt; sgn2 = 1; } else { cs = df - rt; sgn2 = -1; }
  float acs = fabsf(cs);
  float cs1v, sn1v;
  if (acs > ab){
    float ct = -tb/cs;
    sn1v = 1.0f/sqrtf(1.0f + ct*ct);
    cs1v = ct*sn1v;
  } else {
    if (ab == 0.0f){ cs1v = 1.0f; sn1v = 0.0f; }
    else {
      float tn = -cs/tb;
      cs1v = 1.0f/sqrtf(1.0f + tn*tn);
      sn1v = tn*cs1v;
    }
  }
  if (sgn1 == sgn2){ float t = cs1v; cs1v = -sn1v; sn1v = t; }
  *cs1 = cs1v; *sn1 = sn1v;
}

// ssteqr('I', n=4) on per-thread LDS state:
//   st[0..15]  Z (col-major, 1-based macros)
//   st[16..19] D, st[20..24] E, st[25..31] WORK
__device__ void ssteqr4(float* __restrict__ st){
#define Zx(i,j) st[(((j)-1)<<2) + ((i)-1)]
#define Dx(i)   st[16 + ((i)-1)]
#define Ex(i)   st[20 + ((i)-1)]
#define Wx(i)   st[25 + ((i)-1)]
  const int n = 4;
  const float eps    = 5.9604645e-08f;   // slamch('E') fp32
  const float eps2   = eps*eps;
  const float safmin = 1.17549435e-38f;
  const int nmaxit = n*30;
  int jtot = 0;
  #pragma unroll
  for (int j=1;j<=4;j++)
    #pragma unroll
    for (int i=1;i<=4;i++)
      Zx(i,j) = (i==j) ? 1.0f : 0.0f;

  int l1 = 1;
  while (l1 <= n){
    if (l1 > 1) Ex(l1-1) = 0.0f;
    int m = n;
    for (int mm = l1; mm <= n-1; mm++){
      float tst = fabsf(Ex(mm));
      if (tst == 0.0f){ m = mm; break; }
      if (tst <= (sqrtf(fabsf(Dx(mm))) * sqrtf(fabsf(Dx(mm+1)))) * eps){
        Ex(mm) = 0.0f; m = mm; break;
      }
    }
    int l = l1, lsv = l, lend = m, lendsv = lend;
    l1 = m + 1;
    if (lend == l) continue;

    float anorm = 0.0f;
    for (int i=l;i<=lend;i++)   anorm = fmaxf(anorm, fabsf(Dx(i)));
    for (int i=l;i<=lend-1;i++) anorm = fmaxf(anorm, fabsf(Ex(i)));
    if (anorm == 0.0f) continue;
    // scaling (anorm outside [ssfmin,ssfmax]) omitted: inputs O(1)

    if (fabsf(Dx(lend)) < fabsf(Dx(l))){ lend = lsv; l = lendsv; }

    if (lend > l){
      // ---------------- QL iteration ----------------
      for(;;){
        int m2 = lend;
        if (l != lend){
          for (int mm = l; mm <= lend-1; mm++){
            float tst = Ex(mm)*Ex(mm);
            if (tst <= (eps2*fabsf(Dx(mm)))*fabsf(Dx(mm+1)) + safmin){ m2 = mm; break; }
          }
        }
        if (m2 < lend) Ex(m2) = 0.0f;
        float p = Dx(l);
        if (m2 == l){            // eigenvalue found (label 80)
          Dx(l) = p; l = l + 1;
          if (l <= lend) continue;
          break;
        }
        if (m2 == l+1){          // 2x2 block
          float rt1, rt2, c1, s1;
          slaev2f(Dx(l), Ex(l), Dx(l+1), &rt1, &rt2, &c1, &s1);
          Wx(l) = c1; Wx(n-1+l) = s1;
          #pragma unroll
          for (int i=1;i<=4;i++){
            float temp = Zx(i,l+1);
            Zx(i,l+1) = c1*temp - s1*Zx(i,l);
            Zx(i,l)   = s1*temp + c1*Zx(i,l);
          }
          Dx(l) = rt1; Dx(l+1) = rt2; Ex(l) = 0.0f;
          l = l + 2;
          if (l <= lend) continue;
          break;
        }
        if (jtot == nmaxit) break;
        jtot++;
        float g = (Dx(l+1) - p) / (2.0f*Ex(l));
        float r = slapy2f(g, 1.0f);
        g = Dx(m2) - p + (Ex(l) / (g + copysignf(r, g)));
        float s = 1.0f, c = 1.0f;
        p = 0.0f;
        for (int i = m2-1; i >= l; i--){
          float f  = s*Ex(i);
          float bq = c*Ex(i);
          slartgf(g, f, &c, &s, &r);
          if (i != m2-1) Ex(i+1) = r;
          g = Dx(i+1) - p;
          r = (Dx(i) - g)*s + (2.0f*c)*bq;
          p = s*r;
          Dx(i+1) = g + p;
          g = c*r - bq;
          Wx(i) = c;
          Wx(n-1+i) = -s;
        }
        int mmn = m2 - l + 1;    // slasr('R','V','B')
        for (int j = mmn-1; j >= 1; j--){
          float ct = Wx(l+j-1), sx = Wx(n-1+l+j-1);
          if (ct != 1.0f || sx != 0.0f){
            #pragma unroll
            for (int i=1;i<=4;i++){
              float temp = Zx(i, l+j);
              Zx(i, l+j)   = ct*temp - sx*Zx(i, l+j-1);
              Zx(i, l+j-1) = sx*temp + ct*Zx(i, l+j-1);
            }
          }
        }
        Dx(l) = Dx(l) - p;
        Ex(l) = g;
      }
    } else {
      // ---------------- QR iteration ----------------
      for(;;){
        int m2 = lend;
        if (l != lend){
          for (int mm = l; mm >= lend+1; mm--){
            float tst = Ex(mm-1)*Ex(mm-1);
            if (tst <= (eps2*fabsf(Dx(mm)))*fabsf(Dx(mm-1)) + safmin){ m2 = mm; break; }
          }
        }
        if (m2 > lend) Ex(m2-1) = 0.0f;
        float p = Dx(l);
        if (m2 == l){            // label 130
          Dx(l) = p; l = l - 1;
          if (l >= lend) continue;
          break;
        }
        if (m2 == l-1){          // 2x2 block
          float rt1, rt2, c1, s1;
          slaev2f(Dx(l-1), Ex(l-1), Dx(l), &rt1, &rt2, &c1, &s1);
          Wx(m2) = c1; Wx(n-1+m2) = s1;
          #pragma unroll
          for (int i=1;i<=4;i++){
            float temp = Zx(i,l);
            Zx(i,l)   = c1*temp - s1*Zx(i,l-1);
            Zx(i,l-1) = s1*temp + c1*Zx(i,l-1);
          }
          Dx(l-1) = rt1; Dx(l) = rt2; Ex(l-1) = 0.0f;
          l = l - 2;
          if (l >= lend) continue;
          break;
        }
        if (jtot == nmaxit) break;
        jtot++;
        float g = (Dx(l-1) - p) / (2.0f*Ex(l-1));
        float r = slapy2f(g, 1.0f);
        g = Dx(m2) - p + (Ex(l-1) / (g + copysignf(r, g)));
        float s = 1.0f, c = 1.0f;
        p = 0.0f;
        for (int i = m2; i <= l-1; i++){
          float f  = s*Ex(i);
          float bq = c*Ex(i);
          slartgf(g, f, &c, &s, &r);
          if (i != m2) Ex(i-1) = r;
          g = Dx(i) - p;
          r = (Dx(i+1) - g)*s + (2.0f*c)*bq;
          p = s*r;
          Dx(i) = g + p;
          g = c*r - bq;
          Wx(i) = c;
          Wx(n-1+i) = s;
        }
        int mmn = l - m2 + 1;    // slasr('R','V','F')
        for (int j = 1; j <= mmn-1; j++){
          float ct = Wx(m2+j-1), sx = Wx(n-1+m2+j-1);
          if (ct != 1.0f || sx != 0.0f){
            #pragma unroll
            for (int i=1;i<=4;i++){
              float temp = Zx(i, m2+j);
              Zx(i, m2+j)   = ct*temp - sx*Zx(i, m2+j-1);
              Zx(i, m2+j-1) = sx*temp + ct*Zx(i, m2+j-1);
            }
          }
        }
        Dx(l) = Dx(l) - p;
        Ex(l-1) = g;
      }
    }
    if (jtot >= nmaxit) break;
  }
#undef Zx
#undef Dx
#undef Ex
#undef Wx
}

// ---------------- Kernel 1: per-(it,b) model via faithful ssyevd path ----------------

__global__ void __launch_bounds__(64) models_kernel(const float* __restrict__ data,
                                                    const int* __restrict__ idx,
                                                    float* __restrict__ models){
  __shared__ float lds[64*33];
  const int tid = threadIdx.x;
  const int t = blockIdx.x*64 + tid;
  if (t >= NIT*BB) return;
  float* st = &lds[tid*33];
  const int it = t >> 5;
  const int b  = t & 31;

  // gather 3 samples, aug rows [x,y,z,1]
  float P[3][4];
  const int* ip = &idx[(it*BB + b)*3];
  #pragma unroll
  for (int s=0;s<3;s++){
    int n = ip[s];
    const float* pp = &data[((long)b*NPTS + n)*3];
    P[s][0]=pp[0]; P[s][1]=pp[1]; P[s][2]=pp[2]; P[s][3]=1.0f;
  }
  // A = aug^T aug (sum over s in order 0,1,2; separate rounding)
  float A[5][5];
  #pragma unroll
  for (int i=0;i<4;i++)
    #pragma unroll
    for (int j=0;j<4;j++){
      float acc = P[0][i]*P[0][j];
      acc = acc + P[1][i]*P[1][j];
      acc = acc + P[2][i]*P[2][j];
      A[i+1][j+1] = acc;
    }

  // ssytd2 (UPLO='L', n=4): reference-BLAS op ordering
  float eE[5], tauv[4], dD[5];
  #pragma unroll
  for (int i=1;i<=3;i++){
    float alpha = A[i+1][i];
    float ssq = 0.0f;
    #pragma unroll
    for (int k=i+2;k<=4;k++) ssq = ssq + A[k][i]*A[k][i];
    float xnorm = sqrtf(ssq);
    float taui;
    if (xnorm == 0.0f){
      taui = 0.0f;
    } else {
      float beta = -copysignf(slapy2f(alpha, xnorm), alpha);
      taui = (beta - alpha)/beta;
      float sc = 1.0f/(alpha - beta);
      #pragma unroll
      for (int k=i+2;k<=4;k++) A[k][i] = A[k][i]*sc;
      alpha = beta;
    }
    eE[i] = alpha;
    if (taui != 0.0f){
      A[i+1][i] = 1.0f;
      float w[5];
      #pragma unroll
      for (int r=i+1;r<=4;r++) w[r] = 0.0f;
      // ssymv('L'): w = taui * Asub * v
      #pragma unroll
      for (int j=i+1;j<=4;j++){
        float temp1 = taui*A[j][i];
        float temp2 = 0.0f;
        w[j] = w[j] + temp1*A[j][j];
        #pragma unroll
        for (int r=j+1;r<=4;r++){
          w[r] = w[r] + temp1*A[r][j];
          temp2 = temp2 + A[r][j]*A[r][i];
        }
        w[j] = w[j] + taui*temp2;
      }
      // alpha2 = -0.5*taui*dot(w,v); w += alpha2*v
      float dot = 0.0f;
      #pragma unroll
      for (int r=i+1;r<=4;r++) dot = dot + w[r]*A[r][i];
      float alpha2 = (-0.5f*taui)*dot;
      #pragma unroll
      for (int r=i+1;r<=4;r++) w[r] = w[r] + alpha2*A[r][i];
      // ssyr2('L', alpha=-1): A -= v w^T + w v^T (lower)
      #pragma unroll
      for (int j=i+1;j<=4;j++){
        float xj = A[j][i], yj = w[j];
        if (xj != 0.0f || yj != 0.0f){
          float temp1 = -yj;
          float temp2 = -xj;
          #pragma unroll
          for (int r=j;r<=4;r++){
            float acc = A[r][j] + A[r][i]*temp1;
            acc = acc + w[r]*temp2;
            A[r][j] = acc;
          }
        }
      }
    }
    tauv[i] = taui;
  }
  #pragma unroll
  for (int i=1;i<=4;i++) dD[i] = A[i][i];

  // load D/E into LDS state, run ssteqr
  #pragma unroll
  for (int i=1;i<=4;i++) st[16 + i-1] = dD[i];
  st[20+0] = eE[1]; st[20+1] = eE[2]; st[20+2] = eE[3]; st[20+3] = 0.0f; st[20+4] = 0.0f;
  ssteqr4(st);

  // argmin eigenvalue (first minimum — matches ssteqr's selection sort rank-0 pick)
  int kbest = 1;
  float dmin = st[16+0];
  #pragma unroll
  for (int j=2;j<=4;j++){
    float dj = st[16+j-1];
    if (dj < dmin){ dmin = dj; kbest = j; }
  }
  float zc1 = st[((kbest-1)<<2)+0];
  float zc2 = st[((kbest-1)<<2)+1];
  float zc3 = st[((kbest-1)<<2)+2];
  float zc4 = st[((kbest-1)<<2)+3];

  // sormtr: apply Q = H1*H2 (H2 first, then H1); H3 has tau=0
  {
    float v2 = A[4][2];
    float sum = zc3 + v2*zc4;
    float tt = tauv[2]*sum;
    zc3 = zc3 - tt;
    zc4 = zc4 - tt*v2;
  }
  {
    float va = A[3][1], vb = A[4][1];
    float sum = zc2 + va*zc3;
    sum = sum + vb*zc4;
    float tt = tauv[1]*sum;
    zc2 = zc2 - tt;
    zc3 = zc3 - tt*va;
    zc4 = zc4 - tt*vb;
  }

  // reference post-process: normalize by ||(a,b,c)||, sign-fix abc only
  float n2 = zc1*zc1;
  n2 = n2 + zc2*zc2;
  n2 = n2 + zc3*zc3;
  float nrm = sqrtf(n2);
  float a0 = zc1/nrm;
  float b0 = zc2/nrm;
  float c0 = zc3/nrm;
  float d0 = zc4/nrm;
  float sg = (b0 < 0.0f) ? -1.0f : 1.0f;
  a0 = a0*sg; b0 = b0*sg; c0 = c0*sg;

  float* mp = &models[(size_t)(it*BB + b)*4];
  mp[0]=a0; mp[1]=b0; mp[2]=c0; mp[3]=d0;
}

// ---------------- Kernel 2: inlier counting ----------------

__global__ void __launch_bounds__(256) count_kernel(const float* __restrict__ data,
                                                    const float* __restrict__ models,
                                                    int* __restrict__ counts){
  __shared__ float4 smodel[NIT];
  const int b = blockIdx.y;
  const int chunk = blockIdx.x;
  const int t = threadIdx.x;
  if (t < NIT) smodel[t] = ((const float4*)models)[t*BB + b];
  __syncthreads();

  float x[8], y[8], z[8];
  const long base = (long)b*NPTS + (long)chunk*2048;
  #pragma unroll
  for (int k=0;k<8;k++){
    const float* pp = &data[(base + (long)k*256 + t)*3];
    x[k]=pp[0]; y[k]=pp[1]; z[k]=pp[2];
  }
  const int lane = t & 63;
  for (int m=0;m<NIT;m++){
    float4 md = smodel[m];
    int cnt = 0;
    #pragma unroll
    for (int k=0;k<8;k++){
      // numpy einsum order, separate rounding (no FMA): ((a*x + b*y) + c*z) + d
      float s = __fmul_rn(md.x, x[k]);
      s = __fadd_rn(s, __fmul_rn(md.y, y[k]));
      s = __fadd_rn(s, __fmul_rn(md.z, z[k]));
      s = __fadd_rn(s, md.w);
      unsigned long long msk = __ballot(fabsf(s) < 0.05f);
      cnt += (int)__popcll(msk);
    }
    if (lane == 0) atomicAdd(&counts[m*BB + b], cnt);
  }
}

// ---------------- Kernel 3: faithful sequential scan + output ----------------

__global__ void __launch_bounds__(64) scan_kernel(const int* __restrict__ counts,
                                                  const float* __restrict__ models,
                                                  float* __restrict__ out){
  const int lane = threadIdx.x;
  const int b = lane & 31;   // lanes 32..63 mirror, so 64-wide max == max over batches
  int best_ic = 0;
  int best_it = -1;
  bool done = false;
  for (int it=0; it<NIT; it++){
    int ic = counts[it*BB + b];
    bool upd = (ic > best_ic) && (!done);
    if (upd){ best_ic = ic; best_it = it; }
    float p = (float)best_ic / 32768.0f;
    float p3 = (p*p)*p;
    float prob = fminf(1.0f - p3, 0.99f);
    float k = -0.35667494393873245f / (logf(prob) + 1e-10f);
    float kmax = k;
    #pragma unroll
    for (int off=1; off<64; off<<=1){
      float o = __shfl_xor(kmax, off, 64);
      kmax = fmaxf(kmax, o);
    }
    int reason = (int)kmax;          // astype(int32): trunc toward zero
    if (reason > 100) reason = 100;
    done = done || ((it+1) >= reason);
  }
  if (lane < 32){
    float4 m = make_float4(0.0f,0.0f,0.0f,0.0f);
    if (best_it >= 0){
      const float* mp = &models[(size_t)(best_it*BB + b)*4];
      m.x = mp[0]; m.y = mp[1]; m.z = mp[2]; m.w = mp[3];
    }
    ((float4*)out)[b] = m;
  }
}

// ---------------- launch ----------------

extern "C" void kernel_launch(void* const* d_in, const int* in_sizes, int n_in,
                              void* d_out, int out_size, void* d_ws, size_t ws_size,
                              hipStream_t stream){
  const float* data = (const float*)d_in[0];
  const int*   idx  = (const int*)d_in[1];
  float* out = (float*)d_out;
  float* models = (float*)d_ws;                                    // NIT*32*4 floats = 17920 B
  int*   counts = (int*)((char*)d_ws + (size_t)NIT*BB*4*sizeof(float)); // NIT*32 ints

  hipMemsetAsync(counts, 0, (size_t)NIT*BB*sizeof(int), stream);
  models_kernel<<<(NIT*BB + 63)/64, 64, 0, stream>>>(data, idx, models);
  count_kernel<<<dim3(16, BB), 256, 0, stream>>>(data, models, counts);
  scan_kernel<<<1, 64, 0, stream>>>(counts, models, out);
}